// Round 15
// baseline (880.515 us; speedup 1.0000x reference)
//
#include <hip/hip_runtime.h>
#include <hip/hip_bf16.h>

#define NUM_E 64
#define KTOP 8
#define CAP 512
#define TT 2048
#define DD 2048
#define HH 1024

#define BK 32
#define LDSK 36  // B rows 72B: all b64 classes at 4-lane/bank minimum (9 coprime 16)

typedef __attribute__((ext_vector_type(4))) float f4v;
typedef __attribute__((ext_vector_type(8))) short bf16x8;
typedef __attribute__((ext_vector_type(4))) short bf16x4;

static __device__ __forceinline__ short f2bf(float f) {
    __bf16 b = (__bf16)f;
    return __builtin_bit_cast(short, b);
}
static __device__ __forceinline__ int imin(int a, int b) { return a < b ? a : b; }

// direct global->LDS DMA, 16B per lane; dest = wave-uniform base + lane*16
static __device__ __forceinline__ void load_lds16(const ushort* g, ushort* l) {
    __builtin_amdgcn_global_load_lds(
        (const __attribute__((address_space(1))) unsigned int*)g,
        (__attribute__((address_space(3))) unsigned int*)l, 16, 0, 0);
}

// lgkm-only barrier: LDS ops committed; global loads stay in flight.
static __device__ __forceinline__ void pipe_barrier() {
    asm volatile("s_waitcnt lgkmcnt(0)" ::: "memory");
    __builtin_amdgcn_s_barrier();
}

// ---------------- init: zero counts ----------------
__global__ __launch_bounds__(64) void k_init(int* __restrict__ counts) {
    counts[threadIdx.x] = 0;
}

// ---------------- prep: x f32 -> bf16 (stored in out[] region, free 8MB) ----
__global__ __launch_bounds__(256) void k_prep(const float* __restrict__ x,
                                              ushort* __restrict__ xbf) {
    int idx = blockIdx.x * 256 + threadIdx.x;
    size_t i8 = (size_t)idx * 8;
    f4v v0 = *(const f4v*)(x + i8);
    f4v v1 = *(const f4v*)(x + i8 + 4);
    bf16x8 o = {f2bf(v0[0]), f2bf(v0[1]), f2bf(v0[2]), f2bf(v0[3]),
                f2bf(v1[0]), f2bf(v1[1]), f2bf(v1[2]), f2bf(v1[3])};
    *(bf16x8*)(xbf + i8) = o;
}

// ---------------- zero out[] (after gateup consumed xbf, before down) -------
__global__ __launch_bounds__(256) void k_zero(float* __restrict__ out) {
    int idx = blockIdx.x * 256 + threadIdx.x;
    f4v z = {0.f, 0.f, 0.f, 0.f};
    ((f4v*)out)[idx] = z;
}

// ---------------- router: logits = x @ gate_w (f32, exact) ----------------
#define RTOK 8
__global__ __launch_bounds__(256) void k_router(const float* __restrict__ x,
                                                const float* __restrict__ gw,
                                                float* __restrict__ logits) {
    __shared__ float xs[RTOK][512];
    const int tid = threadIdx.x;
    const int lane = tid & 63, wid = tid >> 6;
    const int t0 = blockIdx.x * RTOK;
    float a0 = 0.f, a1 = 0.f;
    for (int c = 0; c < DD / 512; ++c) {
        __syncthreads();
#pragma unroll
        for (int u = tid * 4; u < RTOK * 512; u += 1024) {
            int r = u >> 9, col = u & 511;
            *(f4v*)&xs[r][col] = *(const f4v*)&x[(size_t)(t0 + r) * DD + c * 512 + col];
        }
        __syncthreads();
        const float* gcol = gw + (size_t)c * 512 * NUM_E + lane;
#pragma unroll 8
        for (int d = 0; d < 512; ++d) {
            float g = gcol[(size_t)d * NUM_E];
            a0 = fmaf(xs[wid * 2 + 0][d], g, a0);
            a1 = fmaf(xs[wid * 2 + 1][d], g, a1);
        }
    }
    logits[(size_t)(t0 + wid * 2 + 0) * NUM_E + lane] = a0;
    logits[(size_t)(t0 + wid * 2 + 1) * NUM_E + lane] = a1;
}

// ---------------- topk + dispatch ----------------
__global__ __launch_bounds__(256) void k_topk(const float* __restrict__ logits,
                                              int* __restrict__ counts,
                                              int* __restrict__ slot_token,
                                              float* __restrict__ slot_wt) {
    int lane = threadIdx.x & 63, wid = threadIdx.x >> 6;
    int t = blockIdx.x * 4 + wid;
    float l = logits[(size_t)t * NUM_E + lane];
    float m = l;
#pragma unroll
    for (int off = 32; off; off >>= 1) m = fmaxf(m, __shfl_xor(m, off));
    float ex = __expf(l - m);
    float s = ex;
#pragma unroll
    for (int off = 32; off; off >>= 1) s += __shfl_xor(s, off);
    float p = ex / s;
#pragma unroll
    for (int k = 0; k < KTOP; ++k) {
        float v = p;
        int i = lane;
#pragma unroll
        for (int off = 32; off; off >>= 1) {
            float v2 = __shfl_xor(v, off);
            int i2 = __shfl_xor(i, off);
            if (v2 > v || (v2 == v && i2 < i)) { v = v2; i = i2; }
        }
        if (lane == i) {
            int pos = atomicAdd(&counts[i], 1);
            if (pos < CAP) {
                int slot = i * CAP + pos;
                slot_token[slot] = t;
                slot_wt[slot] = v;
            }
            p = -1.0f;
        }
    }
}

// ================= gate+up fused GEMM + SwiGLU -> h =================
// BM=512 (=CAP: ONE block reads each weight panel -> B CU-volume halved),
// BN=64, BK=32. 1024 threads = 16 waves (8m x 2n); wave 64x32 dual acc (64
// regs, r8-proven). A: global_load_lds DMA, linear [512][32], src-octet XOR.
// B: dual register banks (2-phase load cover), LDSK=36 (r8-proven layout).
// Per phase: ADMA(t+1) | BWRITE(bank, drained) | BLOAD(bank<-t+2) | FM |
// vmcnt(4) (drains A-DMA only) | lgkm barrier.
__global__ __launch_bounds__(1024, 4) void k_gateup(
    const ushort* __restrict__ xbf, const float* __restrict__ wg, const float* __restrict__ wu,
    const int* __restrict__ counts, const int* __restrict__ slot_token,
    const float* __restrict__ slot_wt, ushort* __restrict__ hbuf) {
    const int e = blockIdx.z;
    int count = counts[e];
    if (count > CAP) count = CAP;
    const int ncol0 = blockIdx.x * 64;
    const int tid = threadIdx.x;
    const int lane = tid & 63, wid = tid >> 6;
    const int wm = wid >> 1, wn = wid & 1;
    const int lrow = lane & 15, g4 = lane >> 4;

    __shared__ ushort As0[512 * 32], As1[512 * 32];   // 32KB each
    __shared__ ushort Bg0[64 * LDSK], Bg1[64 * LDSK]; // 4.6KB each
    __shared__ ushort Bu0[64 * LDSK], Bu1[64 * LDSK];

    // A DMA: wave stages rows [wid*32, wid*32+32), 2 instrs x 16 rows.
    // Lane l -> row i*16+(l>>2), slot l&3; source octet (l&3)^(row&3).
    const ushort* aglb[2];
#pragma unroll
    for (int i = 0; i < 2; ++i) {
        int rl = wid * 32 + i * 16 + (lane >> 2);
        int rg = imin(rl, count - 1);
        int tok = slot_token[e * CAP + rg];
        aglb[i] = xbf + (size_t)tok * DD + (((lane & 3) ^ ((lane >> 2) & 3)) * 8);
    }
    // B staging: tid>>9 selects wg/wu; unit = 1 col x 4 k (4 dword loads).
    const int bidx = tid & 511;
    const int bcol = bidx & 63;
    const int bkq = (bidx >> 6) * 4;   // 0,4,..28
    const float* bptr = ((tid & 512) ? wu : wg) + ((size_t)e * DD + bkq) * HH + ncol0 + bcol;
    ushort* bl0 = (tid & 512) ? Bu0 : Bg0;
    ushort* bl1 = (tid & 512) ? Bu1 : Bg1;

    float sbX[4], sbY[4];   // dual B staging banks
    f4v accg[4][2], accu[4][2];
    const f4v fz = {0.f, 0.f, 0.f, 0.f};
#pragma unroll
    for (int m = 0; m < 4; ++m)
#pragma unroll
        for (int n = 0; n < 2; ++n) { accg[m][n] = fz; accu[m][n] = fz; }

#define GU_ADMA(ASB, KO) { \
    load_lds16(aglb[0] + (KO), &ASB[(wid * 32 + 0) * 32]); \
    load_lds16(aglb[1] + (KO), &ASB[(wid * 32 + 16) * 32]); }

#define GU_BLOAD(SB, KO) { \
    _Pragma("unroll") for (int j_ = 0; j_ < 4; ++j_) \
        SB[j_] = bptr[(size_t)((KO) + j_) * HH]; }

#define GU_BWRITE(SB, BLB) { \
    bf16x4 v_ = {f2bf(SB[0]), f2bf(SB[1]), f2bf(SB[2]), f2bf(SB[3])}; \
    *(bf16x4*)&BLB[bcol * LDSK + bkq] = v_; }

#define GU_FM(AS, BG, BU) { \
    bf16x8 af_[4]; \
    _Pragma("unroll") for (int m_ = 0; m_ < 4; ++m_) { \
        const int row_ = wm * 64 + m_ * 16 + lrow; \
        af_[m_] = *(const bf16x8*)&AS[row_ * 32 + ((g4 ^ (row_ & 3)) * 8)]; } \
    _Pragma("unroll") for (int n_ = 0; n_ < 2; ++n_) { \
        const int c_ = (wn * 32 + n_ * 16 + lrow) * LDSK + g4 * 8; \
        union { bf16x8 v8; bf16x4 v4[2]; } ug_, uu_; \
        ug_.v4[0] = *(const bf16x4*)&BG[c_]; ug_.v4[1] = *(const bf16x4*)&BG[c_ + 4]; \
        uu_.v4[0] = *(const bf16x4*)&BU[c_]; uu_.v4[1] = *(const bf16x4*)&BU[c_ + 4]; \
        _Pragma("unroll") for (int m_ = 0; m_ < 4; ++m_) { \
            accg[m_][n_] = __builtin_amdgcn_mfma_f32_16x16x32_bf16(af_[m_], ug_.v8, accg[m_][n_], 0, 0, 0); \
            accu[m_][n_] = __builtin_amdgcn_mfma_f32_16x16x32_bf16(af_[m_], uu_.v8, accu[m_][n_], 0, 0, 0); } } }

    // prologue: A(t0) DMA; bankX<-B0; write; bankX<-B1; bankY<-B2; barrier
    GU_ADMA(As0, 0);
    __builtin_amdgcn_sched_barrier(0);
    GU_BLOAD(sbX, 0);
    GU_BWRITE(sbX, bl0);           // compiler vmcnt(0): drains A(t0) too
    GU_BLOAD(sbX, BK);             // B1
    GU_BLOAD(sbY, 2 * BK);         // B2
    pipe_barrier();

    const int NK = DD / BK;  // 64, even
    for (int kt = 0; kt < NK; kt += 2) {
        const int k1 = (kt + 1) * BK;               // real (kt<=62)
        const int ko3 = imin(kt + 3, NK - 1) * BK;  // clamped tail: dummy loads,
        const int ko4 = imin(kt + 4, NK - 1) * BK;  // never consumed
        // even phase: consume tile kt (As0/bl0); bankX holds B(kt+1)
        GU_ADMA(As1, k1);
        __builtin_amdgcn_sched_barrier(0);
        GU_BWRITE(sbX, bl1);       // B(kt+1): bank drained last phase
        GU_BLOAD(sbX, ko3);        // bankX <- B(kt+3), 2-phase cover
        __builtin_amdgcn_sched_barrier(0);
        GU_FM(As0, Bg0, Bu0);
        asm volatile("s_waitcnt vmcnt(4)" ::: "memory");  // drain A-DMA
        __builtin_amdgcn_sched_barrier(0);
        pipe_barrier();
        // odd phase: consume tile kt+1 (As1/bl1); bankY holds B(kt+2)
        GU_ADMA(As0, imin(kt + 2, NK - 1) * BK);
        __builtin_amdgcn_sched_barrier(0);
        GU_BWRITE(sbY, bl0);       // B(kt+2)
        GU_BLOAD(sbY, ko4);        // bankY <- B(kt+4)
        __builtin_amdgcn_sched_barrier(0);
        GU_FM(As1, Bg1, Bu1);
        asm volatile("s_waitcnt vmcnt(4)" ::: "memory");
        __builtin_amdgcn_sched_barrier(0);
        pipe_barrier();
    }

    // epilogue: h = silu(g)*u * gate-weight, bf16
#pragma unroll
    for (int m = 0; m < 4; ++m) {
#pragma unroll
        for (int r = 0; r < 4; ++r) {
            int row = wm * 64 + m * 16 + g4 * 4 + r;
            if (row < count) {
                float wgt = slot_wt[e * CAP + row];
                size_t base = (size_t)(e * CAP + row) * HH + ncol0 + wn * 32;
#pragma unroll
                for (int n = 0; n < 2; ++n) {
                    float g = accg[m][n][r], uv = accu[m][n][r];
                    float hv = (g / (1.f + __expf(-g))) * uv * wgt;
                    hbuf[base + n * 16 + lrow] = (ushort)f2bf(hv);
                }
            }
        }
    }
}

// ================= down GEMM + scatter-add into out =================
// BM=512, BN=128, BK=32. 1024 threads = 16 waves (8m x 2n); wave 64x64.
__global__ __launch_bounds__(1024, 4) void k_down(
    const ushort* __restrict__ hbuf, const float* __restrict__ wd,
    const int* __restrict__ counts, const int* __restrict__ slot_token,
    float* __restrict__ out) {
    const int e = blockIdx.z;
    int count = counts[e];
    if (count > CAP) count = CAP;
    const int ncol0 = blockIdx.x * 128;
    const int tid = threadIdx.x;
    const int lane = tid & 63, wid = tid >> 6;
    const int wm = wid >> 1, wn = wid & 1;
    const int lrow = lane & 15, g4 = lane >> 4;

    __shared__ ushort As0[512 * 32], As1[512 * 32];   // 32KB each
    __shared__ ushort Bs0[128 * LDSK], Bs1[128 * LDSK];

    const ushort* aglb[2];
#pragma unroll
    for (int i = 0; i < 2; ++i) {
        int rl = wid * 32 + i * 16 + (lane >> 2);
        int rg = imin(rl, count - 1);
        aglb[i] = hbuf + (size_t)(e * CAP + rg) * HH + (((lane & 3) ^ ((lane >> 2) & 3)) * 8);
    }
    // B: unit = 1 col x 4 k; col = tid&127, kq = ((tid>>7)&7)*4
    const int bcol = tid & 127;
    const int bkq = ((tid >> 7) & 7) * 4;
    const float* bptr = wd + ((size_t)e * HH + bkq) * DD + ncol0 + bcol;

    float sbX[4], sbY[4];
    f4v acc[4][4];
    const f4v fz = {0.f, 0.f, 0.f, 0.f};
#pragma unroll
    for (int m = 0; m < 4; ++m)
#pragma unroll
        for (int n = 0; n < 4; ++n) acc[m][n] = fz;

#define DN_ADMA(ASB, KO) { \
    load_lds16(aglb[0] + (KO), &ASB[(wid * 32 + 0) * 32]); \
    load_lds16(aglb[1] + (KO), &ASB[(wid * 32 + 16) * 32]); }

#define DN_BLOAD(SB, KO) { \
    _Pragma("unroll") for (int j_ = 0; j_ < 4; ++j_) \
        SB[j_] = bptr[(size_t)((KO) + j_) * DD]; }

#define DN_BWRITE(SB, BSB) { \
    bf16x4 v_ = {f2bf(SB[0]), f2bf(SB[1]), f2bf(SB[2]), f2bf(SB[3])}; \
    *(bf16x4*)&BSB[bcol * LDSK + bkq] = v_; }

#define DN_FM(AS, BS) { \
    bf16x8 af_[4]; \
    _Pragma("unroll") for (int m_ = 0; m_ < 4; ++m_) { \
        const int row_ = wm * 64 + m_ * 16 + lrow; \
        af_[m_] = *(const bf16x8*)&AS[row_ * 32 + ((g4 ^ (row_ & 3)) * 8)]; } \
    _Pragma("unroll") for (int n_ = 0; n_ < 4; ++n_) { \
        const int c_ = (wn * 64 + n_ * 16 + lrow) * LDSK + g4 * 8; \
        union { bf16x8 v8; bf16x4 v4[2]; } ub_; \
        ub_.v4[0] = *(const bf16x4*)&BS[c_]; ub_.v4[1] = *(const bf16x4*)&BS[c_ + 4]; \
        _Pragma("unroll") for (int m_ = 0; m_ < 4; ++m_) \
            acc[m_][n_] = __builtin_amdgcn_mfma_f32_16x16x32_bf16(af_[m_], ub_.v8, acc[m_][n_], 0, 0, 0); } }

    DN_ADMA(As0, 0);
    __builtin_amdgcn_sched_barrier(0);
    DN_BLOAD(sbX, 0);
    DN_BWRITE(sbX, Bs0);
    DN_BLOAD(sbX, BK);
    DN_BLOAD(sbY, 2 * BK);
    pipe_barrier();

    const int NK = HH / BK;  // 32, even
    for (int kt = 0; kt < NK; kt += 2) {
        const int k1 = (kt + 1) * BK;
        const int ko3 = imin(kt + 3, NK - 1) * BK;
        const int ko4 = imin(kt + 4, NK - 1) * BK;
        DN_ADMA(As1, k1);
        __builtin_amdgcn_sched_barrier(0);
        DN_BWRITE(sbX, Bs1);
        DN_BLOAD(sbX, ko3);
        __builtin_amdgcn_sched_barrier(0);
        DN_FM(As0, Bs0);
        asm volatile("s_waitcnt vmcnt(4)" ::: "memory");
        __builtin_amdgcn_sched_barrier(0);
        pipe_barrier();
        DN_ADMA(As0, imin(kt + 2, NK - 1) * BK);
        __builtin_amdgcn_sched_barrier(0);
        DN_BWRITE(sbY, Bs0);
        DN_BLOAD(sbY, ko4);
        __builtin_amdgcn_sched_barrier(0);
        DN_FM(As1, Bs1);
        asm volatile("s_waitcnt vmcnt(4)" ::: "memory");
        __builtin_amdgcn_sched_barrier(0);
        pipe_barrier();
    }

#pragma unroll
    for (int m = 0; m < 4; ++m) {
#pragma unroll
        for (int r = 0; r < 4; ++r) {
            int row = wm * 64 + m * 16 + g4 * 4 + r;
            if (row < count) {
                int tok = slot_token[e * CAP + row];
                float* obase = out + (size_t)tok * DD + ncol0 + wn * 64;
#pragma unroll
                for (int n = 0; n < 4; ++n) atomicAdd(obase + n * 16 + lrow, acc[m][n][r]);
            }
        }
    }
}

extern "C" void kernel_launch(void* const* d_in, const int* in_sizes, int n_in,
                              void* d_out, int out_size, void* d_ws, size_t ws_size,
                              hipStream_t stream) {
    const float* x = (const float*)d_in[0];       // [1,2048,2048]
    const float* gw = (const float*)d_in[1];      // [2048,64]
    const float* wg = (const float*)d_in[2];      // [64,2048,1024]
    const float* wu = (const float*)d_in[3];      // [64,2048,1024]
    const float* wd = (const float*)d_in[4];      // [64,1024,2048]
    float* out = (float*)d_out;                   // [T*D] then logits [T*E]
    float* logits = out + (size_t)TT * DD;

    char* ws = (char*)d_ws;
    int* counts = (int*)ws;                                      // 256 B
    int* slot_token = (int*)(ws + 1024);                         // 128 KB
    float* slot_wt = (float*)(ws + 1024 + NUM_E * CAP * 4);      // 128 KB
    ushort* hbuf = (ushort*)(ws + 1024 + 2 * NUM_E * CAP * 4);   // 64 MB bf16 [E*CAP][H]
    // xbf (8 MB bf16 copy of x) lives in out[]: written by k_prep, read by
    // k_gateup, erased by k_zero before k_down's atomics.
    ushort* xbf = (ushort*)out;

    k_init<<<1, 64, 0, stream>>>(counts);
    k_prep<<<(TT * DD / 8) / 256, 256, 0, stream>>>(x, xbf);
    k_router<<<TT / RTOK, 256, 0, stream>>>(x, gw, logits);
    k_topk<<<TT / 4, 256, 0, stream>>>(logits, counts, slot_token, slot_wt);
    k_gateup<<<dim3(HH / 64, 1, NUM_E), 1024, 0, stream>>>(xbf, wg, wu, counts, slot_token, slot_wt, hbuf);
    k_zero<<<(TT * DD / 4) / 256, 256, 0, stream>>>(out);
    k_down<<<dim3(DD / 128, 1, NUM_E), 1024, 0, stream>>>(hbuf, wd, counts, slot_token, out);
}